// Round 3
// baseline (146.883 us; speedup 1.0000x reference)
//
#include <hip/hip_runtime.h>
#include <hip/hip_bf16.h>

// Splat scatter-max: fused (transpose || block-sorted multisplit) + gather.
//   local_coordinate: [B=4, H=4, V=8, N=16384] fp32 in [0,1)
//   flattened_index : [B, H, V, N] int32 (values in [0,NC))
//   features        : [B, H*FD=128, N] fp32
//   output          : [B, H*FD, NC=32768] fp32 = max(0, max over pairs)
constexpr int B  = 4;
constexpr int H  = 4;
constexpr int V  = 8;
constexpr int N  = 16384;
constexpr int FD = 32;
constexpr int NC = 32768;
constexpr int BH = B * H;          // 16
constexpr int VN = V * N;          // 131072 pairs per bh
constexpr int NPAIR = BH * VN;     // 2,097,152

constexpr int CB   = 1024;         // coarse buckets per bh (32 cells each)
constexpr int CAPB = 208;          // record cap per bucket (avg 128)
constexpr int TP   = 8192;         // pairs per scatter block
constexpr int SB   = NPAIR / TP;   // 256 scatter blocks
constexpr int TB   = BH * (N / 128); // 2048 transpose blocks

// ---- workspace layout (4-byte units) ----
constexpr size_t OFF_BCNT   = 0;
constexpr size_t OFF_SLOTS  = OFF_BCNT  + (size_t)BH * CB;
constexpr size_t OFF_FEATST = OFF_SLOTS + (size_t)BH * CB * CAPB;

typedef float f32x4 __attribute__((ext_vector_type(4)));   // native vec for nontemporal builtin

__device__ __forceinline__ unsigned short f2bf(float v) {
    unsigned int u = __float_as_uint(v);
    return (unsigned short)((u + 0x7FFFu + ((u >> 16) & 1u)) >> 16);   // RNE
}

// K1 (fused): blocks [0,SB) = multisplit scatter with block-local counting
// sort (linear slot write-out); blocks [SB, SB+TB) = feats transpose -> bf16.
__global__ __launch_bounds__(1024)
void k_prep(const int* __restrict__ idx, const float* __restrict__ lc,
            const float* __restrict__ feats, int* __restrict__ bcnt,
            unsigned int* __restrict__ slots, unsigned short* __restrict__ featsT) {
    __shared__ __align__(16) unsigned char smem[61440];   // 60 KB
    const int tid = threadIdx.x;

    if (blockIdx.x < SB) {
        // ---------------- scatter path ----------------
        unsigned int*   skey   = (unsigned int*)smem;                    // 32 KB [TP]
        unsigned short* scb    = (unsigned short*)(smem + 32768);        // 16 KB [TP]
        int*            s      = (int*)(smem + 49152);                   // 4 KB  [CB]
        int*            cursor = (int*)(smem + 53248);                   // 4 KB  [CB]
        int*            rbase  = (int*)(smem + 57344);                   // 4 KB  [CB]

        const size_t t0 = (size_t)blockIdx.x * TP;
        const int bh = (int)(t0 >> 17);                  // VN = 2^17

        s[tid] = 0;
        __syncthreads();

        // Pass A: histogram coarse buckets (keep idx values in regs)
        const int4* idx4 = (const int4*)(idx + t0);
        int4 c4a[2];
#pragma unroll
        for (int r = 0; r < 2; ++r) {
            int4 c4 = idx4[tid + r * 1024];
            c4a[r] = c4;
            atomicAdd(&s[c4.x >> 5], 1);
            atomicAdd(&s[c4.y >> 5], 1);
            atomicAdd(&s[c4.z >> 5], 1);
            atomicAdd(&s[c4.w >> 5], 1);
        }
        __syncthreads();
        const int myc = s[tid];

        // wave-hierarchical exclusive scan over 1024 buckets (4 barriers, not 20)
        const int lane = tid & 63;
        const int wid  = tid >> 6;
        int inc = myc;
#pragma unroll
        for (int off = 1; off < 64; off <<= 1) {
            int t = __shfl_up(inc, off, 64);
            if (lane >= off) inc += t;
        }
        if (lane == 63) cursor[wid] = inc;              // 16 wave totals
        __syncthreads();
        if (tid < 16) {
            int wv = cursor[tid];
            int winc = wv;
#pragma unroll
            for (int off = 1; off < 16; off <<= 1) {
                int t = __shfl_up(winc, off, 64);
                if (tid >= off) winc += t;
            }
            cursor[16 + tid] = winc - wv;               // exclusive wave base
        }
        __syncthreads();
        const int scanstart = cursor[16 + wid] + inc - myc;
        __syncthreads();                                 // reads done before overwrite

        s[tid]      = scanstart;            // keep for Phase C lookup
        cursor[tid] = scanstart;
        rbase[tid]  = (myc > 0) ? atomicAdd(&bcnt[bh * CB + tid], myc) : 0;
        __syncthreads();

        // Pass B: pack records, place into bucket-sorted LDS order
        const float4* lc4 = (const float4*)(lc + t0);
        const unsigned int nb = (unsigned int)(t0 & (N - 1));
#pragma unroll
        for (int r = 0; r < 2; ++r) {
            int i = tid + r * 1024;
            int4   c4 = c4a[r];
            float4 l4 = lc4[i];
            unsigned int n0 = nb + (unsigned int)(i * 4);
            int cx[4] = {c4.x, c4.y, c4.z, c4.w};
            float lx[4] = {l4.x, l4.y, l4.z, l4.w};
#pragma unroll
            for (int e = 0; e < 4; ++e) {
                unsigned int q = (unsigned int)(lx[e] * 8192.0f);
                unsigned int key = ((unsigned int)(cx[e] & 31) << 27)
                                 | (q << 14) | (n0 + e);
                int cb = cx[e] >> 5;
                int pos = atomicAdd(&cursor[cb], 1);
                skey[pos] = key;
                scb[pos]  = (unsigned short)cb;
            }
        }
        __syncthreads();

        // Phase C: linear write-out (consecutive threads -> consecutive slots)
#pragma unroll
        for (int r = 0; r < 8; ++r) {
            int j  = tid + r * 1024;
            int cb = scb[j];
            int gpos = rbase[cb] + (j - s[cb]);
            if (gpos < CAPB)
                slots[((size_t)bh * CB + cb) * CAPB + gpos] = skey[j];
        }
    } else {
        // ---------------- transpose path ----------------
        float (*tile)[32][33] = (float (*)[32][33])smem;   // 16.9 KB
        int bi  = blockIdx.x - SB;
        int bh  = bi >> 7;
        int n0  = (bi & 127) * 128;
        int sub = tid >> 8;            // 0..3
        int tx  = tid & 31;
        int ty  = (tid >> 5) & 7;
        int nb  = n0 + sub * 32;
#pragma unroll
        for (int fr = 0; fr < 4; ++fr) {
            int f = ty + fr * 8;
            tile[sub][f][tx] = feats[((size_t)bh * FD + f) * N + nb + tx];
        }
        __syncthreads();
#pragma unroll
        for (int nr = 0; nr < 4; ++nr) {
            int n = ty + nr * 8;
            featsT[((size_t)bh * N + nb + n) * FD + tx] = f2bf(tile[sub][tx][n]);
        }
    }
}

// K2: gather-compute. One block = one coarse bucket (32 cells) of one bh.
// Keys are counting-sorted by cell (32 bins) in LDS so the 8-way ILP chunks
// see cell-runs; register running-max collapses each run to ONE LDS atomic,
// and non-positive runs skip the atomic entirely (acc is zero-initialized).
__global__ __launch_bounds__(256)
void k_compute(const int* __restrict__ bcnt, const unsigned int* __restrict__ slots,
               const unsigned short* __restrict__ featsT, float* __restrict__ out) {
    __shared__ unsigned int acc[32][33];
    __shared__ unsigned int kbuf[CAPB];
    __shared__ unsigned int skb[CAPB];
    __shared__ int chist[32];
    __shared__ int ccur[32];
    const int tid = threadIdx.x;
    const int bh  = blockIdx.x >> 10;
    const int cb  = blockIdx.x & (CB - 1);

    int cnt = bcnt[bh * CB + cb];
    if (cnt > CAPB) cnt = CAPB;
    const unsigned int* row = slots + ((size_t)bh * CB + cb) * CAPB;
    if (tid < 32) chist[tid] = 0;
    if (tid < cnt) kbuf[tid] = row[tid];                // cnt <= 208 < 256
    for (int i = tid; i < 32 * 33; i += 256) ((unsigned int*)acc)[i] = 0u;
    __syncthreads();

    // counting sort by cell (top 5 bits of key)
    if (tid < cnt) atomicAdd(&chist[kbuf[tid] >> 27], 1);
    __syncthreads();
    if (tid < 64) {
        int c = (tid < 32) ? chist[tid] : 0;
        int inc = c;
#pragma unroll
        for (int off = 1; off < 32; off <<= 1) {
            int t = __shfl_up(inc, off, 64);
            if (tid >= off) inc += t;
        }
        if (tid < 32) ccur[tid] = inc - c;              // exclusive base
    }
    __syncthreads();
    if (tid < cnt) {
        unsigned int key = kbuf[tid];
        int p = atomicAdd(&ccur[key >> 27], 1);
        skb[p] = key;
    }
    __syncthreads();

    const int g = tid >> 5;            // group 0..7
    const int f = tid & 31;
    const unsigned short* fT = featsT + (size_t)bh * N * FD;
    const int last = cnt - 1;

    for (int r0 = 8 * g; r0 < cnt; r0 += 64) {
        unsigned int k[8];
        float fv[8];
#pragma unroll
        for (int j = 0; j < 8; ++j)
            k[j] = skb[min(r0 + j, last)];             // clamp: idempotent for max
#pragma unroll
        for (int j = 0; j < 8; ++j) {
            int off = (int)((k[j] & 16383u) << 5) | f;
            fv[j] = __uint_as_float((unsigned int)fT[off] << 16);
        }
        float val[8];
#pragma unroll
        for (int j = 0; j < 8; ++j) {
            float coord = ((float)((k[j] >> 14) & 8191u) + 0.5f) * (1.0f / 8192.0f);
            val[j] = coord * fv[j];
        }
        // run-dedup: cells are sorted, so fold same-cell neighbors in registers.
        // k[] is uniform across the 32 lanes of a group -> branches are uniform.
        float run = val[0];
#pragma unroll
        for (int j = 1; j < 8; ++j) {
            if ((k[j] >> 27) == (k[j - 1] >> 27)) {
                run = fmaxf(run, val[j]);
            } else {
                if (run > 0.0f)
                    atomicMax(&acc[k[j - 1] >> 27][f], __float_as_uint(run));
                run = val[j];
            }
        }
        if (run > 0.0f)
            atomicMax(&acc[k[7] >> 27][f], __float_as_uint(run));
    }
    __syncthreads();

    // streaming (non-temporal) 16B store; empty cells naturally write 0
    const int ff = tid >> 3;           // 0..31
    const int c4 = (tid & 7) * 4;      // 0,4,...,28
    f32x4 o;
    o.x = __uint_as_float(acc[c4 + 0][ff]);
    o.y = __uint_as_float(acc[c4 + 1][ff]);
    o.z = __uint_as_float(acc[c4 + 2][ff]);
    o.w = __uint_as_float(acc[c4 + 3][ff]);
    __builtin_nontemporal_store(o,
        reinterpret_cast<f32x4*>(&out[((size_t)(bh * FD + ff)) * NC + cb * 32 + c4]));
}

extern "C" void kernel_launch(void* const* d_in, const int* in_sizes, int n_in,
                              void* d_out, int out_size, void* d_ws, size_t ws_size,
                              hipStream_t stream) {
    const float* lc    = (const float*)d_in[0];
    const int*   idx   = (const int*)  d_in[1];
    const float* feats = (const float*)d_in[2];
    float* out = (float*)d_out;

    int*            bcnt   = (int*)d_ws + OFF_BCNT;
    unsigned int*   slots  = (unsigned int*)d_ws + OFF_SLOTS;
    unsigned short* featsT = (unsigned short*)((unsigned int*)d_ws + OFF_FEATST);

    hipMemsetAsync(bcnt, 0, (size_t)BH * CB * sizeof(int), stream);

    k_prep<<<SB + TB, 1024, 0, stream>>>(idx, lc, feats, bcnt, slots, featsT);
    k_compute<<<BH * CB, 256, 0, stream>>>(bcnt, slots, featsT, out);
}

// Round 4
// 135.511 us; speedup vs baseline: 1.0839x; 1.0839x over previous
//
#include <hip/hip_runtime.h>
#include <hip/hip_bf16.h>

// Splat scatter-max: fused (transpose || block-sorted multisplit) + gather.
//   local_coordinate: [B=4, H=4, V=8, N=16384] fp32 in [0,1)
//   flattened_index : [B, H, V, N] int32 (values in [0,NC))
//   features        : [B, H*FD=128, N] fp32
//   output          : [B, H*FD, NC=32768] fp32 = max(0, max over pairs)
constexpr int B  = 4;
constexpr int H  = 4;
constexpr int V  = 8;
constexpr int N  = 16384;
constexpr int FD = 32;
constexpr int NC = 32768;
constexpr int BH = B * H;          // 16
constexpr int VN = V * N;          // 131072 pairs per bh
constexpr int NPAIR = BH * VN;     // 2,097,152

constexpr int CB   = 1024;         // coarse buckets per bh (32 cells each)
constexpr int CAPB = 208;          // record cap per bucket (avg 128)
constexpr int TP   = 8192;         // pairs per scatter block
constexpr int SB   = NPAIR / TP;   // 256 scatter blocks
constexpr int TB   = BH * (N / 128); // 2048 transpose blocks

// ---- workspace layout (4-byte units) ----
constexpr size_t OFF_BCNT   = 0;
constexpr size_t OFF_SLOTS  = OFF_BCNT  + (size_t)BH * CB;
constexpr size_t OFF_FEATST = OFF_SLOTS + (size_t)BH * CB * CAPB;

typedef float f32x4 __attribute__((ext_vector_type(4)));   // native vec for nontemporal builtin

__device__ __forceinline__ unsigned short f2bf(float v) {
    unsigned int u = __float_as_uint(v);
    return (unsigned short)((u + 0x7FFFu + ((u >> 16) & 1u)) >> 16);   // RNE
}

// K1 (fused): blocks [0,SB) = multisplit scatter with block-local counting
// sort (linear slot write-out); blocks [SB, SB+TB) = feats transpose -> bf16.
__global__ __launch_bounds__(1024)
void k_prep(const int* __restrict__ idx, const float* __restrict__ lc,
            const float* __restrict__ feats, int* __restrict__ bcnt,
            unsigned int* __restrict__ slots, unsigned short* __restrict__ featsT) {
    __shared__ __align__(16) unsigned char smem[61440];   // 60 KB
    const int tid = threadIdx.x;

    if (blockIdx.x < SB) {
        // ---------------- scatter path ----------------
        unsigned int*   skey   = (unsigned int*)smem;                    // 32 KB [TP]
        unsigned short* scb    = (unsigned short*)(smem + 32768);        // 16 KB [TP]
        int*            s      = (int*)(smem + 49152);                   // 4 KB  [CB]
        int*            cursor = (int*)(smem + 53248);                   // 4 KB  [CB]
        int*            rbase  = (int*)(smem + 57344);                   // 4 KB  [CB]

        const size_t t0 = (size_t)blockIdx.x * TP;
        const int bh = (int)(t0 >> 17);                  // VN = 2^17

        s[tid] = 0;
        __syncthreads();

        // Pass A: histogram coarse buckets (keep idx values in regs)
        const int4* idx4 = (const int4*)(idx + t0);
        int4 c4a[2];
#pragma unroll
        for (int r = 0; r < 2; ++r) {
            int4 c4 = idx4[tid + r * 1024];
            c4a[r] = c4;
            atomicAdd(&s[c4.x >> 5], 1);
            atomicAdd(&s[c4.y >> 5], 1);
            atomicAdd(&s[c4.z >> 5], 1);
            atomicAdd(&s[c4.w >> 5], 1);
        }
        __syncthreads();
        const int myc = s[tid];

        // wave-hierarchical exclusive scan over 1024 buckets (4 barriers, not 20)
        const int lane = tid & 63;
        const int wid  = tid >> 6;
        int inc = myc;
#pragma unroll
        for (int off = 1; off < 64; off <<= 1) {
            int t = __shfl_up(inc, off, 64);
            if (lane >= off) inc += t;
        }
        if (lane == 63) cursor[wid] = inc;              // 16 wave totals
        __syncthreads();
        if (tid < 16) {
            int wv = cursor[tid];
            int winc = wv;
#pragma unroll
            for (int off = 1; off < 16; off <<= 1) {
                int t = __shfl_up(winc, off, 64);
                if (tid >= off) winc += t;
            }
            cursor[16 + tid] = winc - wv;               // exclusive wave base
        }
        __syncthreads();
        const int scanstart = cursor[16 + wid] + inc - myc;
        __syncthreads();                                 // reads done before overwrite

        s[tid]      = scanstart;            // keep for Phase C lookup
        cursor[tid] = scanstart;
        rbase[tid]  = (myc > 0) ? atomicAdd(&bcnt[bh * CB + tid], myc) : 0;
        __syncthreads();

        // Pass B: pack records, place into bucket-sorted LDS order
        const float4* lc4 = (const float4*)(lc + t0);
        const unsigned int nb = (unsigned int)(t0 & (N - 1));
#pragma unroll
        for (int r = 0; r < 2; ++r) {
            int i = tid + r * 1024;
            int4   c4 = c4a[r];
            float4 l4 = lc4[i];
            unsigned int n0 = nb + (unsigned int)(i * 4);
            int cx[4] = {c4.x, c4.y, c4.z, c4.w};
            float lx[4] = {l4.x, l4.y, l4.z, l4.w};
#pragma unroll
            for (int e = 0; e < 4; ++e) {
                unsigned int q = (unsigned int)(lx[e] * 8192.0f);
                unsigned int key = ((unsigned int)(cx[e] & 31) << 27)
                                 | (q << 14) | (n0 + e);
                int cb = cx[e] >> 5;
                int pos = atomicAdd(&cursor[cb], 1);
                skey[pos] = key;
                scb[pos]  = (unsigned short)cb;
            }
        }
        __syncthreads();

        // Phase C: linear write-out (consecutive threads -> consecutive slots)
#pragma unroll
        for (int r = 0; r < 8; ++r) {
            int j  = tid + r * 1024;
            int cb = scb[j];
            int gpos = rbase[cb] + (j - s[cb]);
            if (gpos < CAPB)
                slots[((size_t)bh * CB + cb) * CAPB + gpos] = skey[j];
        }
    } else {
        // ---------------- transpose path ----------------
        float (*tile)[32][33] = (float (*)[32][33])smem;   // 16.9 KB
        int bi  = blockIdx.x - SB;
        int bh  = bi >> 7;
        int n0  = (bi & 127) * 128;
        int sub = tid >> 8;            // 0..3
        int tx  = tid & 31;
        int ty  = (tid >> 5) & 7;
        int nb  = n0 + sub * 32;
#pragma unroll
        for (int fr = 0; fr < 4; ++fr) {
            int f = ty + fr * 8;
            tile[sub][f][tx] = feats[((size_t)bh * FD + f) * N + nb + tx];
        }
        __syncthreads();
#pragma unroll
        for (int nr = 0; nr < 4; ++nr) {
            int n = ty + nr * 8;
            featsT[((size_t)bh * N + nb + n) * FD + tx] = f2bf(tile[sub][tx][n]);
        }
    }
}

// K2: gather-compute. One block = one coarse bucket (32 cells) of one bh.
// 16 groups of 16 lanes; each lane owns TWO adjacent features (one dword of
// bf16x2), so a 64-lane wave carries 4 records per instruction stream --
// halving the per-record key-decode/issue cost vs 32-lane groups.
// No sort, no branches in the hot loop (VALU-issue-bound per round-3 PMC).
__global__ __launch_bounds__(256)
void k_compute(const int* __restrict__ bcnt, const unsigned int* __restrict__ slots,
               const unsigned short* __restrict__ featsT, float* __restrict__ out) {
    __shared__ unsigned int acc[32][33];
    __shared__ unsigned int kbuf[CAPB];
    const int tid = threadIdx.x;
    const int bh  = blockIdx.x >> 10;
    const int cb  = blockIdx.x & (CB - 1);

    int cnt = bcnt[bh * CB + cb];
    if (cnt > CAPB) cnt = CAPB;
    const unsigned int* row = slots + ((size_t)bh * CB + cb) * CAPB;
    if (tid < cnt) kbuf[tid] = row[tid];                // cnt <= 208 < 256
    for (int i = tid; i < 32 * 33; i += 256) ((unsigned int*)acc)[i] = 0u;
    __syncthreads();

    const int gi = tid >> 4;           // group 0..15
    const int fl = tid & 15;           // lane handles features 2*fl, 2*fl+1
    const unsigned int* fT32 = (const unsigned int*)(featsT + (size_t)bh * N * FD);
    const int last = cnt - 1;

    for (int r0 = 4 * gi; r0 < cnt; r0 += 64) {
        unsigned int k[4];
        unsigned int w[4];
#pragma unroll
        for (int j = 0; j < 4; ++j)
            k[j] = kbuf[min(r0 + j, last)];            // clamp: idempotent for max
#pragma unroll
        for (int j = 0; j < 4; ++j)
            w[j] = fT32[(int)((k[j] & 16383u) << 4) | fl];   // bf16 pair
#pragma unroll
        for (int j = 0; j < 4; ++j) {
            float coord = ((float)((k[j] >> 14) & 8191u) + 0.5f) * (1.0f / 8192.0f);
            float f0 = __uint_as_float(w[j] << 16);            // feature 2*fl
            float f1 = __uint_as_float(w[j] & 0xFFFF0000u);    // feature 2*fl+1
            float v0 = fmaxf(coord * f0, 0.0f);
            float v1 = fmaxf(coord * f1, 0.0f);
            unsigned int* a = &acc[k[j] >> 27][fl * 2];
            atomicMax(&a[0], __float_as_uint(v0));
            atomicMax(&a[1], __float_as_uint(v1));
        }
    }
    __syncthreads();

    // streaming (non-temporal) 16B store; empty cells naturally write 0
    const int ff = tid >> 3;           // 0..31
    const int c4 = (tid & 7) * 4;      // 0,4,...,28
    f32x4 o;
    o.x = __uint_as_float(acc[c4 + 0][ff]);
    o.y = __uint_as_float(acc[c4 + 1][ff]);
    o.z = __uint_as_float(acc[c4 + 2][ff]);
    o.w = __uint_as_float(acc[c4 + 3][ff]);
    __builtin_nontemporal_store(o,
        reinterpret_cast<f32x4*>(&out[((size_t)(bh * FD + ff)) * NC + cb * 32 + c4]));
}

extern "C" void kernel_launch(void* const* d_in, const int* in_sizes, int n_in,
                              void* d_out, int out_size, void* d_ws, size_t ws_size,
                              hipStream_t stream) {
    const float* lc    = (const float*)d_in[0];
    const int*   idx   = (const int*)  d_in[1];
    const float* feats = (const float*)d_in[2];
    float* out = (float*)d_out;

    int*            bcnt   = (int*)d_ws + OFF_BCNT;
    unsigned int*   slots  = (unsigned int*)d_ws + OFF_SLOTS;
    unsigned short* featsT = (unsigned short*)((unsigned int*)d_ws + OFF_FEATST);

    hipMemsetAsync(bcnt, 0, (size_t)BH * CB * sizeof(int), stream);

    k_prep<<<SB + TB, 1024, 0, stream>>>(idx, lc, feats, bcnt, slots, featsT);
    k_compute<<<BH * CB, 256, 0, stream>>>(bcnt, slots, featsT, out);
}